// Round 13
// baseline (7834.175 us; speedup 1.0000x reference)
//
#include <hip/hip_runtime.h>

typedef short bf16x8 __attribute__((ext_vector_type(8)));
typedef float f32x4 __attribute__((ext_vector_type(4)));

__device__ __forceinline__ unsigned pack2bf(float a, float b) {
  union { float f; unsigned u; } x, y;
  x.f = a; y.f = b;
  unsigned ra = (x.u + 0x7FFFu + ((x.u >> 16) & 1u)) >> 16;
  unsigned rb = (y.u + 0x7FFFu + ((y.u >> 16) & 1u)) & 0xFFFF0000u;
  return ra | rb;
}
__device__ __forceinline__ unsigned short bfu(float f) {
  union { float f; unsigned u; } v; v.f = f;
  return (unsigned short)((v.u + 0x7FFFu + ((v.u >> 16) & 1u)) >> 16);
}
__device__ __forceinline__ float u2f(unsigned u) {
  union { unsigned u; float f; } v; v.u = u; return v.f;
}
__device__ __forceinline__ float sigf(float x) { return 1.f / (1.f + __expf(-x)); }

#define KB 64
#define LDSP 72

// ---------------- xg GEMM for layer 1 (proven rounds 1-12) ----------------
__global__ __launch_bounds__(256) void gemm_bt(
    const float* __restrict__ A0, size_t a_bstride,
    const float* __restrict__ W,
    const float* __restrict__ bias,
    float* __restrict__ out, size_t o_bstride,
    int Mvalid)
{
  __shared__ unsigned short As[64][LDSP];
  __shared__ unsigned short Bs[64][LDSP];
  const int tid = threadIdx.x;
  const int g0 = blockIdx.x * 64;
  const float* Ab = A0 + (size_t)blockIdx.y * a_bstride;
  float* outb = out + (size_t)blockIdx.y * o_bstride;

  const int srow = tid >> 2;
  const int scol = (tid & 3) << 4;
  const int wv = tid >> 6;
  const int lane = tid & 63;
  const int wr = wv >> 1, wc = wv & 1;
  const int lrow = lane & 15;
  const int lk = (lane >> 4) << 3;

  f32x4 acc[2][2];
#pragma unroll
  for (int i = 0; i < 2; ++i)
#pragma unroll
    for (int j = 0; j < 2; ++j)
      acc[i][j] = (f32x4){0.f, 0.f, 0.f, 0.f};

  const float* Aptr = Ab + (size_t)srow * 768 + scol;
  const float* Bptr = W + ((size_t)(g0 + srow)) * 768 + scol;
  const bool aval = srow < Mvalid;

  for (int k0 = 0; k0 < 768; k0 += KB) {
    uint4 ua0, ua1, ub0, ub1;
    if (aval) {
      const float4* qa = (const float4*)(Aptr + k0);
      float4 f0 = qa[0], f1 = qa[1], f2 = qa[2], f3 = qa[3];
      ua0 = make_uint4(pack2bf(f0.x, f0.y), pack2bf(f0.z, f0.w),
                       pack2bf(f1.x, f1.y), pack2bf(f1.z, f1.w));
      ua1 = make_uint4(pack2bf(f2.x, f2.y), pack2bf(f2.z, f2.w),
                       pack2bf(f3.x, f3.y), pack2bf(f3.z, f3.w));
    } else {
      ua0 = make_uint4(0u, 0u, 0u, 0u);
      ua1 = ua0;
    }
    {
      const float4* qb = (const float4*)(Bptr + k0);
      float4 f0 = qb[0], f1 = qb[1], f2 = qb[2], f3 = qb[3];
      ub0 = make_uint4(pack2bf(f0.x, f0.y), pack2bf(f0.z, f0.w),
                       pack2bf(f1.x, f1.y), pack2bf(f1.z, f1.w));
      ub1 = make_uint4(pack2bf(f2.x, f2.y), pack2bf(f2.z, f2.w),
                       pack2bf(f3.x, f3.y), pack2bf(f3.z, f3.w));
    }
    __syncthreads();
    *(uint4*)&As[srow][scol] = ua0;
    *(uint4*)&As[srow][scol + 8] = ua1;
    *(uint4*)&Bs[srow][scol] = ub0;
    *(uint4*)&Bs[srow][scol + 8] = ub1;
    __syncthreads();
#pragma unroll
    for (int kh = 0; kh < 2; ++kh) {
      bf16x8 a0 = *(const bf16x8*)&As[32 * wr + lrow][32 * kh + lk];
      bf16x8 a1 = *(const bf16x8*)&As[32 * wr + 16 + lrow][32 * kh + lk];
      bf16x8 b0 = *(const bf16x8*)&Bs[32 * wc + lrow][32 * kh + lk];
      bf16x8 b1 = *(const bf16x8*)&Bs[32 * wc + 16 + lrow][32 * kh + lk];
      acc[0][0] = __builtin_amdgcn_mfma_f32_16x16x32_bf16(a0, b0, acc[0][0], 0, 0, 0);
      acc[0][1] = __builtin_amdgcn_mfma_f32_16x16x32_bf16(a0, b1, acc[0][1], 0, 0, 0);
      acc[1][0] = __builtin_amdgcn_mfma_f32_16x16x32_bf16(a1, b0, acc[1][0], 0, 0, 0);
      acc[1][1] = __builtin_amdgcn_mfma_f32_16x16x32_bf16(a1, b1, acc[1][1], 0, 0, 0);
    }
  }

  const int lgrp = lane >> 4;
#pragma unroll
  for (int fr = 0; fr < 2; ++fr)
#pragma unroll
    for (int fc = 0; fc < 2; ++fc)
#pragma unroll
      for (int j = 0; j < 4; ++j) {
        int m = 32 * wr + 16 * fr + lgrp * 4 + j;
        int n = 32 * wc + 16 * fc + lrow;
        if (m < Mvalid)
          outb[(size_t)m * 2304 + g0 + n] = acc[fr][fc][j] + bias[g0 + n];
      }
}

// ---- dual-layer wavefront-pipelined persistent kernel ----
// R12 structure; hg exchange packed to bf16 pairs; seq store moved post-arrive.
#define NWG 72
#define EPS 1e-5f
#define INV768 (1.0f / 768.0f)
#define SLOT 24576u  // u32 words per ring slot (96*64*4)

__device__ __forceinline__ void bar_arrive(unsigned* c) {
  __syncthreads();  // drains vmcnt: sc1 stores at coherence point before arrive
  if (threadIdx.x == 0)
    __hip_atomic_fetch_add(c + (blockIdx.x & 7) * 32, 1u,
                           __ATOMIC_RELAXED, __HIP_MEMORY_SCOPE_AGENT);
}
__device__ __forceinline__ void bar_wait(unsigned* c, unsigned tgt) {
  if (threadIdx.x == 0) {
    for (;;) {
      unsigned s = 0;
#pragma unroll
      for (int i = 0; i < 8; ++i)
        s += __hip_atomic_load(c + i * 32, __ATOMIC_RELAXED, __HIP_MEMORY_SCOPE_AGENT);
      if (s >= tgt) break;
      __builtin_amdgcn_s_sleep(1);
    }
  }
  __syncthreads();
}

template <int N>
__device__ __forceinline__ void blk_reduce(float* v, float* lds) {
#pragma unroll
  for (int k = 0; k < N; ++k) {
    float x = v[k];
#pragma unroll
    for (int off = 1; off < 64; off <<= 1) x += __shfl_xor(x, off);
    v[k] = x;
  }
  const int wv = threadIdx.x >> 6;
  const int lane = threadIdx.x & 63;
  if (lane == 0) {
#pragma unroll
    for (int k = 0; k < N; ++k) lds[wv * N + k] = v[k];
  }
  __syncthreads();
#pragma unroll
  for (int k = 0; k < N; ++k)
    v[k] = lds[k] + lds[N + k] + lds[2 * N + k] + lds[3 * N + k];
  __syncthreads();
}

#define WAITV(n) do { asm volatile("s_waitcnt vmcnt(" #n ")" ::: "memory"); \
                      __builtin_amdgcn_sched_barrier(0); } while (0)

// sc0|sc1 coherence-point ring loads (proven)
#define LD24(buf, base) \
  { _Pragma("unroll") for (int kk_ = 0; kk_ < 24; ++kk_) { \
      const unsigned* p_ = (base) + (size_t)kk_ * 1024u; \
      asm volatile("global_load_dwordx4 %0, %1, off sc0 sc1" : "=v"(buf[kk_]) : "v"(p_)); } }

// write packed bf16 pairs into ring slot (proven sc1 write-through pattern)
#define WRRING(ring, t, val) \
  { unsigned* rp_ = (ring) + (unsigned)(((t) & 3)) * SLOT; \
    _Pragma("unroll") for (int p_ = 0; p_ < 3; ++p_) { \
      int i_ = tid + (p_ << 8); \
      float other_ = __shfl_xor(val[p_], 1); \
      if ((tid & 1) == 0) { \
        unsigned pk_ = pack2bf(val[p_], other_); \
        __hip_atomic_store(rp_ + (i_ >> 3) * 256 + b * 4 + ((i_ >> 1) & 3), pk_, \
                           __ATOMIC_RELAXED, __HIP_MEMORY_SCOPE_AGENT); } } }

__global__ __launch_bounds__(256, 1) void gru_super(
    const float* __restrict__ Whh1, const float* __restrict__ bhh1,
    const float* __restrict__ Wih2, const float* __restrict__ bih2,
    const float* __restrict__ Whh2, const float* __restrict__ bhh2,
    const float* __restrict__ lnw, const float* __restrict__ lnb,  // [2][3][768]
    const float* __restrict__ x,      // [64][512][768]
    const float* __restrict__ xg1,    // [64][TC][2304]
    int t0, int TC,
    const float* __restrict__ h0,     // [2][64][768]
    float* __restrict__ hstate,       // [2][64][768]
    unsigned* __restrict__ h1ring, unsigned* __restrict__ s1ring,
    unsigned* __restrict__ h2ring,
    unsigned* __restrict__ hg1, unsigned* __restrict__ xg2, unsigned* __restrict__ hg2,
    unsigned* __restrict__ bar,
    float* __restrict__ seq,          // d_out [64][512][768]
    float* __restrict__ hfin,         // d_out tail [2][64][768]
    int firstflag, int lastflag)
{
  __shared__ unsigned short Wl[96][776];  // 96 rows of ONE matrix (class-specialized)
  __shared__ float bl96[96];
  __shared__ float redl[32];

  unsigned* barA = bar;
  unsigned* barB = bar + 512;

  const int wg = blockIdx.x;
  const int tid = threadIdx.x;
  const int lane = tid & 63;
  const int w = tid >> 6;
  const int la = lane & 15;
  const int kb = lane >> 4;
  const int arow = 16 * w + la;
  const int mcls = wg / 24;            // 0: Whh1, 1: Wih2, 2: Whh2
  const int g0w = (wg % 24) * 96;      // this WG's 96 gate rows
  const unsigned abase = (unsigned)((kb * 64 + arow) << 2);

  // ---- stage this WG's matrix slice ----
  {
    const float* Wsrc = (mcls == 0) ? Whh1 : (mcls == 1) ? Wih2 : Whh2;
    const float* bsrc = (mcls == 0) ? bhh1 : (mcls == 1) ? bih2 : bhh2;
    for (int r = 0; r < 96; ++r) {
      const float* src = Wsrc + (size_t)(g0w + r) * 768;
      for (int c = tid; c < 768; c += 256) Wl[r][c] = bfu(src[c]);
    }
    if (tid < 96) bl96[tid] = bsrc[g0w + tid];
  }
  unsigned* dst = (mcls == 0) ? hg1 : (mcls == 1) ? xg2 : hg2;

  // ---- consumer init (WGs 0-63 own one batch, both layers) ----
  const int b = wg;
  float hreg1[3] = {0.f,0.f,0.f}, hreg2[3] = {0.f,0.f,0.f};
  float h1prev[3] = {0.f,0.f,0.f}, xprev[3] = {0.f,0.f,0.f}, xcur[3] = {0.f,0.f,0.f};
  float lw1[9], lb1[9], lw2[9], lb2[9];
  if (wg < 64) {
#pragma unroll
    for (int g = 0; g < 3; ++g)
#pragma unroll
      for (int p = 0; p < 3; ++p) {
        int idx = g * 3 + p, gi = g * 768 + tid + (p << 8);
        lw1[idx] = lnw[gi];          lb1[idx] = lnb[gi];
        lw2[idx] = lnw[2304 + gi];   lb2[idx] = lnb[2304 + gi];
      }
#pragma unroll
    for (int p = 0; p < 3; ++p) {
      int i = tid + (p << 8);
      hreg1[p] = firstflag ? h0[(size_t)b * 768 + i] : hstate[(size_t)b * 768 + i];
      hreg2[p] = firstflag ? h0[49152 + (size_t)b * 768 + i] : hstate[49152 + (size_t)b * 768 + i];
      h1prev[p] = hreg1[p];
    }
    if (firstflag) {
      WRRING(h1ring, 3, hreg1);
      WRRING(h2ring, 3, hreg2);
    }
  }
  bar_arrive(barB);
  bar_wait(barB, NWG);

  for (int s = 0; s <= TC; ++s) {
    const int t1 = t0 + s;              // layer-1 timestep
    const bool doL1 = (s < TC);
    const bool doL2 = (s >= 1);
    const bool active = (mcls == 0) ? doL1 : doL2;

    // ---- phase A: one 96-row x 64-batch GEMM from this WG's single ring ----
    if (active) {
      const unsigned* rbase =
          (mcls == 0) ? (h1ring + (unsigned)((t1 - 1) & 3) * SLOT)
        : (mcls == 1) ? (s1ring + (unsigned)((t1 - 1) & 3) * SLOT)
                      : (h2ring + (unsigned)((t1 - 2) & 3) * SLOT);
      const unsigned* hb = rbase + abase;
      f32x4 acc[6];
#pragma unroll
      for (int r = 0; r < 6; ++r) acc[r] = (f32x4){0.f, 0.f, 0.f, 0.f};
      bf16x8 buf[24];
      LD24(buf, hb);
      WAITV(0);
#pragma unroll
      for (int kk = 0; kk < 24; ++kk) {
#pragma unroll
        for (int r = 0; r < 6; ++r) {
          bf16x8 wv = *(const bf16x8*)&Wl[16 * r + la][kk * 32 + kb * 8];
          acc[r] = __builtin_amdgcn_mfma_f32_16x16x32_bf16(buf[kk], wv, acc[r], 0, 0, 0);
        }
      }
      // packed bf16 hg stores: even-la lane packs (own col, la+1 col)
#pragma unroll
      for (int r = 0; r < 6; ++r) {
        int col = g0w + 16 * r + la;
#pragma unroll
        for (int j = 0; j < 4; ++j) {
          int bb = 16 * w + kb * 4 + j;
          float v = acc[r][j] + bl96[16 * r + la];
          float o = __shfl_xor(v, 1);
          if ((la & 1) == 0) {
            unsigned pk = pack2bf(v, o);
            __hip_atomic_store(dst + (size_t)bb * 1152 + (col >> 1), pk,
                               __ATOMIC_RELAXED, __HIP_MEMORY_SCOPE_AGENT);
          }
        }
      }
    }

    // hoist x(t1) for this step (plain cached; used by L2 next step)
    if (wg < 64 && doL1) {
#pragma unroll
      for (int p = 0; p < 3; ++p)
        xcur[p] = x[((size_t)b * 512 + t1) * 768 + tid + (p << 8)];
    }

    bar_arrive(barA);
    bar_wait(barA, (unsigned)(s + 1) * NWG);

    // ---- phase B (WGs 0-63): both layers' LN + gates + updates ----
    float seqv[3];
    bool wr_seq = false;
    if (wg < 64) {
      const int ttc = doL1 ? s : (TC - 1);
      unsigned w1[9], w2[9], w3[9];
      float x1v[9];
      {
        const float* xg1b = xg1 + ((size_t)b * TC + ttc) * 2304;
        const unsigned* p1 = hg1 + (size_t)b * 1152;
        const unsigned* p2 = xg2 + (size_t)b * 1152;
        const unsigned* p3 = hg2 + (size_t)b * 1152;
#pragma unroll
        for (int p = 0; p < 9; ++p) {
          x1v[p] = xg1b[tid + p * 256];
          unsigned idx = (unsigned)(tid + p * 256) >> 1;
          const unsigned* q1 = p1 + idx;
          const unsigned* q2 = p2 + idx;
          const unsigned* q3 = p3 + idx;
          asm volatile("global_load_dword %0, %1, off sc0 sc1" : "=v"(w1[p]) : "v"(q1));
          asm volatile("global_load_dword %0, %1, off sc0 sc1" : "=v"(w2[p]) : "v"(q2));
          asm volatile("global_load_dword %0, %1, off sc0 sc1" : "=v"(w3[p]) : "v"(q3));
        }
      }
      WAITV(0);
      float g1v[9], g2v[9], g3v[9];
      const bool hi = (tid & 1);
#pragma unroll
      for (int p = 0; p < 9; ++p) {
        g1v[p] = hi ? u2f(w1[p] & 0xFFFF0000u) : u2f(w1[p] << 16);
        g2v[p] = hi ? u2f(w2[p] & 0xFFFF0000u) : u2f(w2[p] << 16);
        g3v[p] = hi ? u2f(w3[p] & 0xFFFF0000u) : u2f(w3[p] << 16);
      }

      float s11[3], s21[3], s12[3], s22[3];
      float v8[8] = {0,0,0,0,0,0,0,0};
#pragma unroll
      for (int p = 0; p < 3; ++p) {
        s11[p] = g1v[p] + x1v[p];            // L1 r-gate pre
        s21[p] = g1v[3 + p] + x1v[3 + p];    // L1 z-gate pre
        s12[p] = g2v[p] + g3v[p];            // L2 r-gate pre
        s22[p] = g2v[3 + p] + g3v[3 + p];    // L2 z-gate pre
        v8[0] += s11[p]; v8[1] += s11[p] * s11[p];
        v8[2] += s21[p]; v8[3] += s21[p] * s21[p];
        v8[4] += s12[p]; v8[5] += s12[p] * s12[p];
        v8[6] += s22[p]; v8[7] += s22[p] * s22[p];
      }
      blk_reduce<8>(v8, redl);
      float mu11 = v8[0] * INV768, rs11 = rsqrtf(v8[1] * INV768 - mu11 * mu11 + EPS);
      float mu21 = v8[2] * INV768, rs21 = rsqrtf(v8[3] * INV768 - mu21 * mu21 + EPS);
      float mu12 = v8[4] * INV768, rs12 = rsqrtf(v8[5] * INV768 - mu12 * mu12 + EPS);
      float mu22 = v8[6] * INV768, rs22 = rsqrtf(v8[7] * INV768 - mu22 * mu22 + EPS);

      float z1[3], m1[3], z2[3], m2[3];
      float v4[4] = {0,0,0,0};
#pragma unroll
      for (int p = 0; p < 3; ++p) {
        float r1 = sigf((s11[p] - mu11) * rs11 * lw1[p] + lb1[p]);
        z1[p]    = sigf((s21[p] - mu21) * rs21 * lw1[3 + p] + lb1[3 + p]);
        m1[p] = x1v[6 + p] + r1 * g1v[6 + p];
        float r2 = sigf((s12[p] - mu12) * rs12 * lw2[p] + lb2[p]);
        z2[p]    = sigf((s22[p] - mu22) * rs22 * lw2[3 + p] + lb2[3 + p]);
        m2[p] = g2v[6 + p] + r2 * g3v[6 + p];
        v4[0] += m1[p]; v4[1] += m1[p] * m1[p];
        v4[2] += m2[p]; v4[3] += m2[p] * m2[p];
      }
      blk_reduce<4>(v4, redl);
      float mum1 = v4[0] * INV768, rsm1 = rsqrtf(v4[1] * INV768 - mum1 * mum1 + EPS);
      float mum2 = v4[2] * INV768, rsm2 = rsqrtf(v4[3] * INV768 - mum2 * mum2 + EPS);

      float h1new[3], s1new[3], h2new[3];
#pragma unroll
      for (int p = 0; p < 3; ++p) {
        float n1 = tanhf((m1[p] - mum1) * rsm1 * lw1[6 + p] + lb1[6 + p]);
        h1new[p] = (1.f - z1[p]) * n1 + z1[p] * hreg1[p];
        s1new[p] = h1new[p] + xcur[p];
        float n2 = tanhf((m2[p] - mum2) * rsm2 * lw2[6 + p] + lb2[6 + p]);
        h2new[p] = (1.f - z2[p]) * n2 + z2[p] * hreg2[p];
      }
      if (doL2) {
#pragma unroll
        for (int p = 0; p < 3; ++p) {
          hreg2[p] = h2new[p];
          seqv[p] = h2new[p] + h1prev[p] + xprev[p];  // stored after arrive
        }
        wr_seq = true;
        WRRING(h2ring, t1 - 1, h2new);
      }
      if (doL1) {
#pragma unroll
        for (int p = 0; p < 3; ++p) {
          hreg1[p] = h1new[p];
          h1prev[p] = h1new[p];
          xprev[p] = xcur[p];
        }
        WRRING(h1ring, t1, h1new);
        WRRING(s1ring, t1, s1new);
      }
    }
    bar_arrive(barB);
    // seq HBM store issued post-arrive: drains during the next spin window
    if (wr_seq) {
      const int t2 = t1 - 1;
#pragma unroll
      for (int p = 0; p < 3; ++p) {
        int i = tid + (p << 8);
        seq[((size_t)b * 512 + t2) * 768 + i] = seqv[p];
      }
    }
    bar_wait(barB, (unsigned)(s + 2) * NWG);
  }

  if (wg < 64) {
#pragma unroll
    for (int p = 0; p < 3; ++p) {
      int i = tid + (p << 8);
      hstate[(size_t)b * 768 + i] = hreg1[p];
      hstate[49152 + (size_t)b * 768 + i] = hreg2[p];
      if (lastflag) {
        hfin[(size_t)b * 768 + i] = hreg1[p];
        hfin[49152 + (size_t)b * 768 + i] = hreg2[p];
      }
    }
  }
}

extern "C" void kernel_launch(void* const* d_in, const int* in_sizes, int n_in,
                              void* d_out, int out_size, void* d_ws, size_t ws_size,
                              hipStream_t stream) {
  const float* x    = (const float*)d_in[0];
  const float* h0   = (const float*)d_in[1];
  const float* w_ih = (const float*)d_in[2];
  const float* b_ih = (const float*)d_in[3];
  const float* w_hh = (const float*)d_in[4];
  const float* b_hh = (const float*)d_in[5];
  const float* lnw  = (const float*)d_in[6];
  const float* lnb  = (const float*)d_in[7];
  float* out = (float*)d_out;

  const int B = 64, T = 512, H = 768, G = 2304;

  const size_t BAR = 65536;
  const size_t RING = 4u * SLOT * 4u;       // 393,216 B per ring
  const size_t HGB = (size_t)B * G * 4;     // region size kept (uses half, packed)
  int CHUNK = 64;
  for (;;) {
    size_t need = BAR + 3 * RING + 3 * HGB + 2 * (size_t)B * H * 4
                + (size_t)B * CHUNK * G * 4;
    if (need <= ws_size || CHUNK == 8) break;
    CHUNK >>= 1;
  }

  char* wp = (char*)d_ws;
  unsigned* barctr = (unsigned*)wp;            wp += BAR;
  unsigned* h1ring = (unsigned*)wp;            wp += RING;
  unsigned* s1ring = (unsigned*)wp;            wp += RING;
  unsigned* h2ring = (unsigned*)wp;            wp += RING;
  unsigned* hg1 = (unsigned*)wp;               wp += HGB;
  unsigned* xg2 = (unsigned*)wp;               wp += HGB;
  unsigned* hg2 = (unsigned*)wp;               wp += HGB;
  float* hstate = (float*)wp;                  wp += 2 * (size_t)B * H * 4;
  float* xg1 = (float*)wp;

  hipMemsetAsync(barctr, 0, BAR, stream);

  float* seq  = out;
  float* hfin = out + (size_t)B * T * H;
  const int NCH = T / CHUNK;

  const float* Wih1 = w_ih;
  const float* Wih2 = w_ih + (size_t)G * H;
  const float* Whh1 = w_hh;
  const float* Whh2 = w_hh + (size_t)G * H;

  for (int c = 0; c < NCH; ++c) {
    int t0 = c * CHUNK;
    gemm_bt<<<dim3(G / 64, B), 256, 0, stream>>>(
        x + (size_t)t0 * H, (size_t)T * H, Wih1, b_ih,
        xg1, (size_t)CHUNK * G, CHUNK);
    gru_super<<<NWG, 256, 0, stream>>>(
        Whh1, b_hh, Wih2, b_ih + G, Whh2, b_hh + G,
        lnw, lnb, x, xg1, t0, CHUNK,
        h0, hstate, h1ring, s1ring, h2ring,
        hg1, xg2, hg2,
        barctr + (size_t)c * 1024,
        seq, hfin,
        (c == 0) ? 1 : 0, (c == NCH - 1) ? 1 : 0);
  }
}

// Round 15
// 6638.951 us; speedup vs baseline: 1.1800x; 1.1800x over previous
//
#include <hip/hip_runtime.h>

typedef short bf16x8 __attribute__((ext_vector_type(8)));
typedef float f32x4 __attribute__((ext_vector_type(4)));

__device__ __forceinline__ unsigned pack2bf(float a, float b) {
  union { float f; unsigned u; } x, y;
  x.f = a; y.f = b;
  unsigned ra = (x.u + 0x7FFFu + ((x.u >> 16) & 1u)) >> 16;
  unsigned rb = (y.u + 0x7FFFu + ((y.u >> 16) & 1u)) & 0xFFFF0000u;
  return ra | rb;
}
__device__ __forceinline__ unsigned short bfu(float f) {
  union { float f; unsigned u; } v; v.f = f;
  return (unsigned short)((v.u + 0x7FFFu + ((v.u >> 16) & 1u)) >> 16);
}
__device__ __forceinline__ float sigf(float x) { return 1.f / (1.f + __expf(-x)); }

#define KB 64
#define LDSP 72

// ---------------- xg GEMM for layer 1 ----------------
// M tiled by blockIdx.z: each z-block computes 64 timestep-rows.
__global__ __launch_bounds__(256) void gemm_bt(
    const float* __restrict__ A0, size_t a_bstride,
    const float* __restrict__ W,
    const float* __restrict__ bias,
    float* __restrict__ out, size_t o_bstride,
    int Mvalid)
{
  __shared__ unsigned short As[64][LDSP];
  __shared__ unsigned short Bs[64][LDSP];
  const int tid = threadIdx.x;
  const int g0 = blockIdx.x * 64;
  const int mlo = blockIdx.z * 64;
  const float* Ab = A0 + (size_t)blockIdx.y * a_bstride + (size_t)mlo * 768;
  float* outb = out + (size_t)blockIdx.y * o_bstride + (size_t)mlo * 2304;

  const int srow = tid >> 2;
  const int scol = (tid & 3) << 4;
  const int wv = tid >> 6;
  const int lane = tid & 63;
  const int wr = wv >> 1, wc = wv & 1;
  const int lrow = lane & 15;
  const int lk = (lane >> 4) << 3;

  f32x4 acc[2][2];
#pragma unroll
  for (int i = 0; i < 2; ++i)
#pragma unroll
    for (int j = 0; j < 2; ++j)
      acc[i][j] = (f32x4){0.f, 0.f, 0.f, 0.f};

  const float* Aptr = Ab + (size_t)srow * 768 + scol;
  const float* Bptr = W + ((size_t)(g0 + srow)) * 768 + scol;
  const bool aval = (mlo + srow) < Mvalid;

  for (int k0 = 0; k0 < 768; k0 += KB) {
    uint4 ua0, ua1, ub0, ub1;
    if (aval) {
      const float4* qa = (const float4*)(Aptr + k0);
      float4 f0 = qa[0], f1 = qa[1], f2 = qa[2], f3 = qa[3];
      ua0 = make_uint4(pack2bf(f0.x, f0.y), pack2bf(f0.z, f0.w),
                       pack2bf(f1.x, f1.y), pack2bf(f1.z, f1.w));
      ua1 = make_uint4(pack2bf(f2.x, f2.y), pack2bf(f2.z, f2.w),
                       pack2bf(f3.x, f3.y), pack2bf(f3.z, f3.w));
    } else {
      ua0 = make_uint4(0u, 0u, 0u, 0u);
      ua1 = ua0;
    }
    {
      const float4* qb = (const float4*)(Bptr + k0);
      float4 f0 = qb[0], f1 = qb[1], f2 = qb[2], f3 = qb[3];
      ub0 = make_uint4(pack2bf(f0.x, f0.y), pack2bf(f0.z, f0.w),
                       pack2bf(f1.x, f1.y), pack2bf(f1.z, f1.w));
      ub1 = make_uint4(pack2bf(f2.x, f2.y), pack2bf(f2.z, f2.w),
                       pack2bf(f3.x, f3.y), pack2bf(f3.z, f3.w));
    }
    __syncthreads();
    *(uint4*)&As[srow][scol] = ua0;
    *(uint4*)&As[srow][scol + 8] = ua1;
    *(uint4*)&Bs[srow][scol] = ub0;
    *(uint4*)&Bs[srow][scol + 8] = ub1;
    __syncthreads();
#pragma unroll
    for (int kh = 0; kh < 2; ++kh) {
      bf16x8 a0 = *(const bf16x8*)&As[32 * wr + lrow][32 * kh + lk];
      bf16x8 a1 = *(const bf16x8*)&As[32 * wr + 16 + lrow][32 * kh + lk];
      bf16x8 b0 = *(const bf16x8*)&Bs[32 * wc + lrow][32 * kh + lk];
      bf16x8 b1 = *(const bf16x8*)&Bs[32 * wc + 16 + lrow][32 * kh + lk];
      acc[0][0] = __builtin_amdgcn_mfma_f32_16x16x32_bf16(a0, b0, acc[0][0], 0, 0, 0);
      acc[0][1] = __builtin_amdgcn_mfma_f32_16x16x32_bf16(a0, b1, acc[0][1], 0, 0, 0);
      acc[1][0] = __builtin_amdgcn_mfma_f32_16x16x32_bf16(a1, b0, acc[1][0], 0, 0, 0);
      acc[1][1] = __builtin_amdgcn_mfma_f32_16x16x32_bf16(a1, b1, acc[1][1], 0, 0, 0);
    }
  }

  const int lgrp = lane >> 4;
#pragma unroll
  for (int fr = 0; fr < 2; ++fr)
#pragma unroll
    for (int fc = 0; fc < 2; ++fc)
#pragma unroll
      for (int j = 0; j < 4; ++j) {
        int m = 32 * wr + 16 * fr + lgrp * 4 + j;
        int n = 32 * wc + 16 * fc + lrow;
        if (mlo + m < Mvalid)
          outb[(size_t)m * 2304 + g0 + n] = acc[fr][fc][j] + bias[g0 + n];
      }
}

// ---- dual-layer wavefront-pipelined persistent kernel, ROLE-SPLIT ----
// 72 pure producer WGs (wg 0-71: 24 per matrix, 96 rows each)
// 64 pure consumer WGs (wg 72-135: one batch each)
// Each WG polls exactly ONE barrier per round.
#define NWGP 72
#define NWGC 64
#define NWGT 136
#define EPS 1e-5f
#define INV768 (1.0f / 768.0f)
#define SLOT 24576u  // u32 words per ring slot (96*64*4)

__device__ __forceinline__ void bar_arrive(unsigned* c) {
  __syncthreads();  // drains vmcnt: sc1 stores at coherence point before arrive
  if (threadIdx.x == 0)
    __hip_atomic_fetch_add(c + (blockIdx.x & 7) * 32, 1u,
                           __ATOMIC_RELAXED, __HIP_MEMORY_SCOPE_AGENT);
}
__device__ __forceinline__ void bar_wait(unsigned* c, unsigned tgt) {
  if (threadIdx.x == 0) {
    for (;;) {
      unsigned s = 0;
#pragma unroll
      for (int i = 0; i < 8; ++i)
        s += __hip_atomic_load(c + i * 32, __ATOMIC_RELAXED, __HIP_MEMORY_SCOPE_AGENT);
      if (s >= tgt) break;
      __builtin_amdgcn_s_sleep(1);
    }
  }
  __syncthreads();
}

template <int N>
__device__ __forceinline__ void blk_reduce(float* v, float* lds) {
#pragma unroll
  for (int k = 0; k < N; ++k) {
    float x = v[k];
#pragma unroll
    for (int off = 1; off < 64; off <<= 1) x += __shfl_xor(x, off);
    v[k] = x;
  }
  const int wv = threadIdx.x >> 6;
  const int lane = threadIdx.x & 63;
  if (lane == 0) {
#pragma unroll
    for (int k = 0; k < N; ++k) lds[wv * N + k] = v[k];
  }
  __syncthreads();
#pragma unroll
  for (int k = 0; k < N; ++k)
    v[k] = lds[k] + lds[N + k] + lds[2 * N + k] + lds[3 * N + k];
  __syncthreads();
}

#define WAITV(n) do { asm volatile("s_waitcnt vmcnt(" #n ")" ::: "memory"); \
                      __builtin_amdgcn_sched_barrier(0); } while (0)

// sc0|sc1 coherence-point ring loads (proven)
#define LD24(buf, base) \
  { _Pragma("unroll") for (int kk_ = 0; kk_ < 24; ++kk_) { \
      const unsigned* p_ = (base) + (size_t)kk_ * 1024u; \
      asm volatile("global_load_dwordx4 %0, %1, off sc0 sc1" : "=v"(buf[kk_]) : "v"(p_)); } }

// write packed bf16 pairs into ring slot (proven sc1 write-through pattern)
#define WRRING(ring, t, val) \
  { unsigned* rp_ = (ring) + (unsigned)(((t) & 3)) * SLOT; \
    _Pragma("unroll") for (int p_ = 0; p_ < 3; ++p_) { \
      int i_ = tid + (p_ << 8); \
      float other_ = __shfl_xor(val[p_], 1); \
      if ((tid & 1) == 0) { \
        unsigned pk_ = pack2bf(val[p_], other_); \
        __hip_atomic_store(rp_ + (i_ >> 3) * 256 + b * 4 + ((i_ >> 1) & 3), pk_, \
                           __ATOMIC_RELAXED, __HIP_MEMORY_SCOPE_AGENT); } } }

__global__ __launch_bounds__(256, 1) void gru_super(
    const float* __restrict__ Whh1, const float* __restrict__ bhh1,
    const float* __restrict__ Wih2, const float* __restrict__ bih2,
    const float* __restrict__ Whh2, const float* __restrict__ bhh2,
    const float* __restrict__ lnw, const float* __restrict__ lnb,  // [2][3][768]
    const float* __restrict__ x,      // [64][512][768]
    const float* __restrict__ xg1,    // [64][TC][2304]
    int t0, int TC,
    const float* __restrict__ h0,     // [2][64][768]
    float* __restrict__ hstate,       // [2][64][768]
    unsigned* __restrict__ h1ring, unsigned* __restrict__ s1ring,
    unsigned* __restrict__ h2ring,
    float* __restrict__ hg1, float* __restrict__ xg2, float* __restrict__ hg2,
    unsigned* __restrict__ bar,
    float* __restrict__ seq,          // d_out [64][512][768]
    float* __restrict__ hfin,         // d_out tail [2][64][768]
    int firstflag, int lastflag)
{
  __shared__ unsigned short Wl[96][776];
  __shared__ float bl96[96];
  __shared__ float redl[32];

  unsigned* barA = bar;
  unsigned* barB = bar + 512;

  const int wg = blockIdx.x;
  const int tid = threadIdx.x;
  const int lane = tid & 63;
  const int w = tid >> 6;
  const int la = lane & 15;
  const int kb = lane >> 4;
  const int arow = 16 * w + la;

  if (wg < NWGP) {
    // ================= PRODUCER (phase A only) =================
    const int mcls = wg / 24;            // 0: Whh1, 1: Wih2, 2: Whh2
    const int g0w = (wg % 24) * 96;
    const unsigned abase = (unsigned)((kb * 64 + arow) << 2);
    {
      const float* Wsrc = (mcls == 0) ? Whh1 : (mcls == 1) ? Wih2 : Whh2;
      const float* bsrc = (mcls == 0) ? bhh1 : (mcls == 1) ? bih2 : bhh2;
      for (int r = 0; r < 96; ++r) {
        const float* src = Wsrc + (size_t)(g0w + r) * 768;
        for (int c = tid; c < 768; c += 256) Wl[r][c] = bfu(src[c]);
      }
      if (tid < 96) bl96[tid] = bsrc[g0w + tid];
    }
    float* dst = (mcls == 0) ? hg1 : (mcls == 1) ? xg2 : hg2;

    for (int s = 0; s <= TC; ++s) {
      const int t1 = t0 + s;
      const bool active = (mcls == 0) ? (s < TC) : (s >= 1);
      bar_wait(barB, 64u * (unsigned)(s + 1));  // ring data for this round ready
      if (active) {
        const unsigned* rbase =
            (mcls == 0) ? (h1ring + (unsigned)((t1 - 1) & 3) * SLOT)
          : (mcls == 1) ? (s1ring + (unsigned)((t1 - 1) & 3) * SLOT)
                        : (h2ring + (unsigned)((t1 - 2) & 3) * SLOT);
        const unsigned* hb = rbase + abase;
        f32x4 acc[6];
#pragma unroll
        for (int r = 0; r < 6; ++r) acc[r] = (f32x4){0.f, 0.f, 0.f, 0.f};
        bf16x8 buf[24];
        LD24(buf, hb);
        WAITV(0);
#pragma unroll
        for (int kk = 0; kk < 24; ++kk) {
#pragma unroll
          for (int r = 0; r < 6; ++r) {
            bf16x8 wv2 = *(const bf16x8*)&Wl[16 * r + la][kk * 32 + kb * 8];
            acc[r] = __builtin_amdgcn_mfma_f32_16x16x32_bf16(buf[kk], wv2, acc[r], 0, 0, 0);
          }
        }
#pragma unroll
        for (int r = 0; r < 6; ++r)
#pragma unroll
          for (int j = 0; j < 4; ++j) {
            int bb = 16 * w + kb * 4 + j;
            __hip_atomic_store(dst + (size_t)bb * 2304 + g0w + 16 * r + la,
                               acc[r][j] + bl96[16 * r + la],
                               __ATOMIC_RELAXED, __HIP_MEMORY_SCOPE_AGENT);
          }
      }
      bar_arrive(barA);   // syncthreads drains hg stores, then count
    }
    return;
  }

  // ================= CONSUMER (phase B only) =================
  const int b = wg - NWGP;
  float hreg1[3], hreg2[3];
  float h1prev[3], xprev[3] = {0.f, 0.f, 0.f}, xcur[3] = {0.f, 0.f, 0.f};
  float lw1[9], lb1[9], lw2[9], lb2[9];
#pragma unroll
  for (int g = 0; g < 3; ++g)
#pragma unroll
    for (int p = 0; p < 3; ++p) {
      int idx = g * 3 + p, gi = g * 768 + tid + (p << 8);
      lw1[idx] = lnw[gi];          lb1[idx] = lnb[gi];
      lw2[idx] = lnw[2304 + gi];   lb2[idx] = lnb[2304 + gi];
    }
#pragma unroll
  for (int p = 0; p < 3; ++p) {
    int i = tid + (p << 8);
    hreg1[p] = firstflag ? h0[(size_t)b * 768 + i] : hstate[(size_t)b * 768 + i];
    hreg2[p] = firstflag ? h0[49152 + (size_t)b * 768 + i] : hstate[49152 + (size_t)b * 768 + i];
    h1prev[p] = hreg1[p];
  }
  if (firstflag) {
    WRRING(h1ring, 3, hreg1);   // (t0-1)&3 == 3 for t0 multiple of 4
    WRRING(h2ring, 3, hreg2);
  }
  bar_arrive(barB);   // init arrival: producers may start round 0

  for (int s = 0; s <= TC; ++s) {
    const int t1 = t0 + s;
    const bool doL1 = (s < TC);
    const bool doL2 = (s >= 1);

    // hoist read-only loads (prior-dispatch data, plain cached) during phase A
    const int ttc = doL1 ? s : (TC - 1);
    float x1v[9];
    {
      const float* xg1b = xg1 + ((size_t)b * TC + ttc) * 2304;
#pragma unroll
      for (int p = 0; p < 9; ++p) x1v[p] = xg1b[tid + p * 256];
    }
    if (doL1) {
#pragma unroll
      for (int p = 0; p < 3; ++p)
        xcur[p] = x[((size_t)b * 512 + t1) * 768 + tid + (p << 8)];
    }

    bar_wait(barA, 72u * (unsigned)(s + 1));   // hg1/xg2/hg2 for this round ready

    float g1v[9], g2v[9], g3v[9];
    {
      const float* p1 = hg1 + (size_t)b * 2304;
      const float* p2 = xg2 + (size_t)b * 2304;
      const float* p3 = hg2 + (size_t)b * 2304;
#pragma unroll
      for (int p = 0; p < 9; ++p) {
        const float* q1 = p1 + tid + p * 256;
        const float* q2 = p2 + tid + p * 256;
        const float* q3 = p3 + tid + p * 256;
        asm volatile("global_load_dword %0, %1, off sc0 sc1" : "=v"(g1v[p]) : "v"(q1));
        asm volatile("global_load_dword %0, %1, off sc0 sc1" : "=v"(g2v[p]) : "v"(q2));
        asm volatile("global_load_dword %0, %1, off sc0 sc1" : "=v"(g3v[p]) : "v"(q3));
      }
    }
    WAITV(0);

    float s11[3], s21[3], s12[3], s22[3];
    float v8[8] = {0,0,0,0,0,0,0,0};
#pragma unroll
    for (int p = 0; p < 3; ++p) {
      s11[p] = g1v[p] + x1v[p];
      s21[p] = g1v[3 + p] + x1v[3 + p];
      s12[p] = g2v[p] + g3v[p];
      s22[p] = g2v[3 + p] + g3v[3 + p];
      v8[0] += s11[p]; v8[1] += s11[p] * s11[p];
      v8[2] += s21[p]; v8[3] += s21[p] * s21[p];
      v8[4] += s12[p]; v8[5] += s12[p] * s12[p];
      v8[6] += s22[p]; v8[7] += s22[p] * s22[p];
    }
    blk_reduce<8>(v8, redl);
    float mu11 = v8[0] * INV768, rs11 = rsqrtf(v8[1] * INV768 - mu11 * mu11 + EPS);
    float mu21 = v8[2] * INV768, rs21 = rsqrtf(v8[3] * INV768 - mu21 * mu21 + EPS);
    float mu12 = v8[4] * INV768, rs12 = rsqrtf(v8[5] * INV768 - mu12 * mu12 + EPS);
    float mu22 = v8[6] * INV768, rs22 = rsqrtf(v8[7] * INV768 - mu22 * mu22 + EPS);

    float z1[3], m1[3], z2[3], m2[3];
    float v4[4] = {0,0,0,0};
#pragma unroll
    for (int p = 0; p < 3; ++p) {
      float r1 = sigf((s11[p] - mu11) * rs11 * lw1[p] + lb1[p]);
      z1[p]    = sigf((s21[p] - mu21) * rs21 * lw1[3 + p] + lb1[3 + p]);
      m1[p] = x1v[6 + p] + r1 * g1v[6 + p];
      float r2 = sigf((s12[p] - mu12) * rs12 * lw2[p] + lb2[p]);
      z2[p]    = sigf((s22[p] - mu22) * rs22 * lw2[3 + p] + lb2[3 + p]);
      m2[p] = g2v[6 + p] + r2 * g3v[6 + p];
      v4[0] += m1[p]; v4[1] += m1[p] * m1[p];
      v4[2] += m2[p]; v4[3] += m2[p] * m2[p];
    }
    blk_reduce<4>(v4, redl);
    float mum1 = v4[0] * INV768, rsm1 = rsqrtf(v4[1] * INV768 - mum1 * mum1 + EPS);
    float mum2 = v4[2] * INV768, rsm2 = rsqrtf(v4[3] * INV768 - mum2 * mum2 + EPS);

    float h1new[3], s1new[3], h2new[3], seqv[3];
#pragma unroll
    for (int p = 0; p < 3; ++p) {
      float n1 = tanhf((m1[p] - mum1) * rsm1 * lw1[6 + p] + lb1[6 + p]);
      h1new[p] = (1.f - z1[p]) * n1 + z1[p] * hreg1[p];
      s1new[p] = h1new[p] + xcur[p];
      float n2 = tanhf((m2[p] - mum2) * rsm2 * lw2[6 + p] + lb2[6 + p]);
      h2new[p] = (1.f - z2[p]) * n2 + z2[p] * hreg2[p];
    }
    if (doL2) {
#pragma unroll
      for (int p = 0; p < 3; ++p) {
        hreg2[p] = h2new[p];
        seqv[p] = h2new[p] + h1prev[p] + xprev[p];
      }
      WRRING(h2ring, t1 - 1, h2new);
    }
    if (doL1) {
#pragma unroll
      for (int p = 0; p < 3; ++p) {
        hreg1[p] = h1new[p];
        h1prev[p] = h1new[p];
        xprev[p] = xcur[p];
      }
      WRRING(h1ring, t1, h1new);
      WRRING(s1ring, t1, s1new);
    }
    bar_arrive(barB);   // drains ring writes, then count
    // seq HBM store post-arrive: drains during the next barA poll window
    if (doL2) {
      const int t2 = t1 - 1;
#pragma unroll
      for (int p = 0; p < 3; ++p) {
        int i = tid + (p << 8);
        seq[((size_t)b * 512 + t2) * 768 + i] = seqv[p];
      }
    }
  }

#pragma unroll
  for (int p = 0; p < 3; ++p) {
    int i = tid + (p << 8);
    hstate[(size_t)b * 768 + i] = hreg1[p];
    hstate[49152 + (size_t)b * 768 + i] = hreg2[p];
    if (lastflag) {
      hfin[(size_t)b * 768 + i] = hreg1[p];
      hfin[49152 + (size_t)b * 768 + i] = hreg2[p];
    }
  }
}

extern "C" void kernel_launch(void* const* d_in, const int* in_sizes, int n_in,
                              void* d_out, int out_size, void* d_ws, size_t ws_size,
                              hipStream_t stream) {
  const float* x    = (const float*)d_in[0];
  const float* h0   = (const float*)d_in[1];
  const float* w_ih = (const float*)d_in[2];
  const float* b_ih = (const float*)d_in[3];
  const float* w_hh = (const float*)d_in[4];
  const float* b_hh = (const float*)d_in[5];
  const float* lnw  = (const float*)d_in[6];
  const float* lnb  = (const float*)d_in[7];
  float* out = (float*)d_out;

  const int B = 64, T = 512, H = 768, G = 2304;

  const size_t BAR = 65536;
  const size_t RING = 4u * SLOT * 4u;       // 393,216 B per ring
  const size_t HGB = (size_t)B * G * 4;     // 589,824 B
  int CHUNK = 128;
  for (;;) {
    size_t need = BAR + 3 * RING + 3 * HGB + 2 * (size_t)B * H * 4
                + (size_t)B * CHUNK * G * 4;
    if (need <= ws_size || CHUNK == 8) break;
    CHUNK >>= 1;
  }

  char* wp = (char*)d_ws;
  unsigned* barctr = (unsigned*)wp;            wp += BAR;
  unsigned* h1ring = (unsigned*)wp;            wp += RING;
  unsigned* s1ring = (unsigned*)wp;            wp += RING;
  unsigned* h2ring = (unsigned*)wp;            wp += RING;
  float* hg1 = (float*)wp;                     wp += HGB;
  float* xg2 = (float*)wp;                     wp += HGB;
  float* hg2 = (float*)wp;                     wp += HGB;
  float* hstate = (float*)wp;                  wp += 2 * (size_t)B * H * 4;
  float* xg1 = (float*)wp;

  hipMemsetAsync(barctr, 0, BAR, stream);

  float* seq  = out;
  float* hfin = out + (size_t)B * T * H;
  const int NCH = T / CHUNK;

  const float* Wih1 = w_ih;
  const float* Wih2 = w_ih + (size_t)G * H;
  const float* Whh1 = w_hh;
  const float* Whh2 = w_hh + (size_t)G * H;

  for (int c = 0; c < NCH; ++c) {
    int t0 = c * CHUNK;
    gemm_bt<<<dim3(G / 64, B, CHUNK / 64), 256, 0, stream>>>(
        x + (size_t)t0 * H, (size_t)T * H, Wih1, b_ih,
        xg1, (size_t)CHUNK * G, CHUNK);
    gru_super<<<NWGT, 256, 0, stream>>>(
        Whh1, b_hh, Wih2, b_ih + G, Whh2, b_hh + G,
        lnw, lnb, x, xg1, t0, CHUNK,
        h0, hstate, h1ring, s1ring, h2ring,
        hg1, xg2, hg2,
        barctr + (size_t)c * 1024,
        seq, hfin,
        (c == 0) ? 1 : 0, (c == NCH - 1) ? 1 : 0);
  }
}

// Round 18
// 6499.322 us; speedup vs baseline: 1.2054x; 1.0215x over previous
//
#include <hip/hip_runtime.h>

typedef short bf16x8 __attribute__((ext_vector_type(8)));
typedef float f32x4 __attribute__((ext_vector_type(4)));

__device__ __forceinline__ unsigned pack2bf(float a, float b) {
  union { float f; unsigned u; } x, y;
  x.f = a; y.f = b;
  unsigned ra = (x.u + 0x7FFFu + ((x.u >> 16) & 1u)) >> 16;
  unsigned rb = (y.u + 0x7FFFu + ((y.u >> 16) & 1u)) & 0xFFFF0000u;
  return ra | rb;
}
__device__ __forceinline__ unsigned short bfu(float f) {
  union { float f; unsigned u; } v; v.f = f;
  return (unsigned short)((v.u + 0x7FFFu + ((v.u >> 16) & 1u)) >> 16);
}
__device__ __forceinline__ float u2f(unsigned u) {
  union { unsigned u; float f; } v; v.u = u; return v.f;
}
__device__ __forceinline__ float sigf(float x) { return 1.f / (1.f + __expf(-x)); }

#define KB 64
#define LDSP 72

// ---------------- xg GEMM for layer 1 (proven; M tiled by blockIdx.z) ----------------
__global__ __launch_bounds__(256) void gemm_bt(
    const float* __restrict__ A0, size_t a_bstride,
    const float* __restrict__ W,
    const float* __restrict__ bias,
    float* __restrict__ out, size_t o_bstride,
    int Mvalid)
{
  __shared__ unsigned short As[64][LDSP];
  __shared__ unsigned short Bs[64][LDSP];
  const int tid = threadIdx.x;
  const int g0 = blockIdx.x * 64;
  const int mlo = blockIdx.z * 64;
  const float* Ab = A0 + (size_t)blockIdx.y * a_bstride + (size_t)mlo * 768;
  float* outb = out + (size_t)blockIdx.y * o_bstride + (size_t)mlo * 2304;

  const int srow = tid >> 2;
  const int scol = (tid & 3) << 4;
  const int wv = tid >> 6;
  const int lane = tid & 63;
  const int wr = wv >> 1, wc = wv & 1;
  const int lrow = lane & 15;
  const int lk = (lane >> 4) << 3;

  f32x4 acc[2][2];
#pragma unroll
  for (int i = 0; i < 2; ++i)
#pragma unroll
    for (int j = 0; j < 2; ++j)
      acc[i][j] = (f32x4){0.f, 0.f, 0.f, 0.f};

  const float* Aptr = Ab + (size_t)srow * 768 + scol;
  const float* Bptr = W + ((size_t)(g0 + srow)) * 768 + scol;
  const bool aval = (mlo + srow) < Mvalid;

  for (int k0 = 0; k0 < 768; k0 += KB) {
    uint4 ua0, ua1, ub0, ub1;
    if (aval) {
      const float4* qa = (const float4*)(Aptr + k0);
      float4 f0 = qa[0], f1 = qa[1], f2 = qa[2], f3 = qa[3];
      ua0 = make_uint4(pack2bf(f0.x, f0.y), pack2bf(f0.z, f0.w),
                       pack2bf(f1.x, f1.y), pack2bf(f1.z, f1.w));
      ua1 = make_uint4(pack2bf(f2.x, f2.y), pack2bf(f2.z, f2.w),
                       pack2bf(f3.x, f3.y), pack2bf(f3.z, f3.w));
    } else {
      ua0 = make_uint4(0u, 0u, 0u, 0u);
      ua1 = ua0;
    }
    {
      const float4* qb = (const float4*)(Bptr + k0);
      float4 f0 = qb[0], f1 = qb[1], f2 = qb[2], f3 = qb[3];
      ub0 = make_uint4(pack2bf(f0.x, f0.y), pack2bf(f0.z, f0.w),
                       pack2bf(f1.x, f1.y), pack2bf(f1.z, f1.w));
      ub1 = make_uint4(pack2bf(f2.x, f2.y), pack2bf(f2.z, f2.w),
                       pack2bf(f3.x, f3.y), pack2bf(f3.z, f3.w));
    }
    __syncthreads();
    *(uint4*)&As[srow][scol] = ua0;
    *(uint4*)&As[srow][scol + 8] = ua1;
    *(uint4*)&Bs[srow][scol] = ub0;
    *(uint4*)&Bs[srow][scol + 8] = ub1;
    __syncthreads();
#pragma unroll
    for (int kh = 0; kh < 2; ++kh) {
      bf16x8 a0 = *(const bf16x8*)&As[32 * wr + lrow][32 * kh + lk];
      bf16x8 a1 = *(const bf16x8*)&As[32 * wr + 16 + lrow][32 * kh + lk];
      bf16x8 b0 = *(const bf16x8*)&Bs[32 * wc + lrow][32 * kh + lk];
      bf16x8 b1 = *(const bf16x8*)&Bs[32 * wc + 16 + lrow][32 * kh + lk];
      acc[0][0] = __builtin_amdgcn_mfma_f32_16x16x32_bf16(a0, b0, acc[0][0], 0, 0, 0);
      acc[0][1] = __builtin_amdgcn_mfma_f32_16x16x32_bf16(a0, b1, acc[0][1], 0, 0, 0);
      acc[1][0] = __builtin_amdgcn_mfma_f32_16x16x32_bf16(a1, b0, acc[1][0], 0, 0, 0);
      acc[1][1] = __builtin_amdgcn_mfma_f32_16x16x32_bf16(a1, b1, acc[1][1], 0, 0, 0);
    }
  }

  const int lgrp = lane >> 4;
#pragma unroll
  for (int fr = 0; fr < 2; ++fr)
#pragma unroll
    for (int fc = 0; fc < 2; ++fc)
#pragma unroll
      for (int j = 0; j < 4; ++j) {
        int m = 32 * wr + 16 * fr + lgrp * 4 + j;
        int n = 32 * wc + 16 * fc + lrow;
        if (mlo + m < Mvalid)
          outb[(size_t)m * 2304 + g0 + n] = acc[fr][fc][j] + bias[g0 + n];
      }
}

// ---- R15 skeleton + consumer split: 72 producers, 64 C1 (L1), 64 C2 (L2) ----
// ONE barrier pair (proven topology): producers wait barB (128/round), arrive barA;
// consumers wait barA (72/round), arrive barB.
#define NWGT 200
#define EPS 1e-5f
#define INV768 (1.0f / 768.0f)
#define SLOT 24576u   // u32 words per ring slot (96*64*4)

__device__ __forceinline__ void bar_arrive(unsigned* c) {
  __syncthreads();  // drains vmcnt: sc1 stores at coherence point before arrive
  if (threadIdx.x == 0)
    __hip_atomic_fetch_add(c + (blockIdx.x & 7) * 32, 1u,
                           __ATOMIC_RELAXED, __HIP_MEMORY_SCOPE_AGENT);
}
__device__ __forceinline__ void bar_wait(unsigned* c, unsigned tgt) {
  if (threadIdx.x == 0) {
    for (;;) {
      unsigned s = 0;
#pragma unroll
      for (int i = 0; i < 8; ++i)
        s += __hip_atomic_load(c + i * 32, __ATOMIC_RELAXED, __HIP_MEMORY_SCOPE_AGENT);
      if (s >= tgt) break;
      __builtin_amdgcn_s_sleep(1);
    }
  }
  __syncthreads();
}

template <int N>
__device__ __forceinline__ void blk_reduce(float* v, float* lds) {
#pragma unroll
  for (int k = 0; k < N; ++k) {
    float x = v[k];
#pragma unroll
    for (int off = 1; off < 64; off <<= 1) x += __shfl_xor(x, off);
    v[k] = x;
  }
  const int wv = threadIdx.x >> 6;
  const int lane = threadIdx.x & 63;
  if (lane == 0) {
#pragma unroll
    for (int k = 0; k < N; ++k) lds[wv * N + k] = v[k];
  }
  __syncthreads();
#pragma unroll
  for (int k = 0; k < N; ++k)
    v[k] = lds[k] + lds[N + k] + lds[2 * N + k] + lds[3 * N + k];
  __syncthreads();
}

#define WAITV(n) do { asm volatile("s_waitcnt vmcnt(" #n ")" ::: "memory"); \
                      __builtin_amdgcn_sched_barrier(0); } while (0)

#define LD24(buf, base) \
  { _Pragma("unroll") for (int kk_ = 0; kk_ < 24; ++kk_) { \
      const unsigned* p_ = (base) + (size_t)kk_ * 1024u; \
      asm volatile("global_load_dwordx4 %0, %1, off sc0 sc1" : "=v"(buf[kk_]) : "v"(p_)); } }

#define WRRING(ring, t, val) \
  { unsigned* rp_ = (ring) + (unsigned)(((t) & 3)) * SLOT; \
    _Pragma("unroll") for (int p_ = 0; p_ < 3; ++p_) { \
      int i_ = tid + (p_ << 8); \
      float other_ = __shfl_xor(val[p_], 1); \
      if ((tid & 1) == 0) { \
        unsigned pk_ = pack2bf(val[p_], other_); \
        __hip_atomic_store(rp_ + (i_ >> 3) * 256 + b * 4 + ((i_ >> 1) & 3), pk_, \
                           __ATOMIC_RELAXED, __HIP_MEMORY_SCOPE_AGENT); } } }

__global__ __launch_bounds__(256, 1) void gru_super(
    const float* __restrict__ Whh1, const float* __restrict__ bhh1,
    const float* __restrict__ Wih2, const float* __restrict__ bih2,
    const float* __restrict__ Whh2, const float* __restrict__ bhh2,
    const float* __restrict__ lnw, const float* __restrict__ lnb,  // [2][3][768]
    const float* __restrict__ x,      // [64][512][768]
    const float* __restrict__ xg1,    // [64][TC][2304]
    int t0, int TC,
    const float* __restrict__ h0,     // [2][64][768]
    float* __restrict__ hstate,       // [2][64][768]
    unsigned* __restrict__ h1ring, unsigned* __restrict__ s1ring,
    unsigned* __restrict__ h2ring,
    float* __restrict__ hg1, float* __restrict__ xg2, float* __restrict__ hg2,
    unsigned* __restrict__ bar,
    float* __restrict__ seq,          // d_out [64][512][768]
    float* __restrict__ hfin,         // d_out tail [2][64][768]
    int firstflag, int lastflag)
{
  __shared__ unsigned short Wl[96][776];
  __shared__ float bl96[96];
  __shared__ float redl[32];

  unsigned* barA = bar;
  unsigned* barB = bar + 512;

  const int wg = blockIdx.x;
  const int tid = threadIdx.x;
  const int lane = tid & 63;
  const int w = tid >> 6;
  const int la = lane & 15;
  const int kb = lane >> 4;
  const int arow = 16 * w + la;

  if (wg < 72) {
    // ================= PRODUCERS (verbatim R15; barB target x2) =================
    const int mcls = wg / 24;            // 0: Whh1->hg1, 1: Wih2->xg2, 2: Whh2->hg2
    const int g0w = (wg % 24) * 96;
    const unsigned abase = (unsigned)((kb * 64 + arow) << 2);
    {
      const float* Wsrc = (mcls == 0) ? Whh1 : (mcls == 1) ? Wih2 : Whh2;
      const float* bsrc = (mcls == 0) ? bhh1 : (mcls == 1) ? bih2 : bhh2;
      for (int r = 0; r < 96; ++r) {
        const float* src = Wsrc + (size_t)(g0w + r) * 768;
        for (int c = tid; c < 768; c += 256) Wl[r][c] = bfu(src[c]);
      }
      if (tid < 96) bl96[tid] = bsrc[g0w + tid];
    }
    float* dst = (mcls == 0) ? hg1 : (mcls == 1) ? xg2 : hg2;

    for (int s = 0; s <= TC; ++s) {
      const int t1 = t0 + s;
      const bool doL1 = (s < TC);
      const bool doL2 = (s >= 1);
      const bool active = (mcls == 0) ? doL1 : doL2;
      bar_wait(barB, 128u * (unsigned)(s + 1));   // both consumer sets thru round s-1
      if (active) {
        const unsigned* rbase =
            (mcls == 0) ? (h1ring + (unsigned)((t1 - 1) & 3) * SLOT)
          : (mcls == 1) ? (s1ring + (unsigned)((t1 - 1) & 3) * SLOT)
                        : (h2ring + (unsigned)((t1 - 2) & 3) * SLOT);
        const unsigned* hb = rbase + abase;
        f32x4 acc[6];
#pragma unroll
        for (int q = 0; q < 6; ++q) acc[q] = (f32x4){0.f, 0.f, 0.f, 0.f};
        bf16x8 buf[24];
        LD24(buf, hb);
        WAITV(0);
#pragma unroll
        for (int kk = 0; kk < 24; ++kk) {
#pragma unroll
          for (int q = 0; q < 6; ++q) {
            bf16x8 wv2 = *(const bf16x8*)&Wl[16 * q + la][kk * 32 + kb * 8];
            acc[q] = __builtin_amdgcn_mfma_f32_16x16x32_bf16(buf[kk], wv2, acc[q], 0, 0, 0);
          }
        }
#pragma unroll
        for (int q = 0; q < 6; ++q)
#pragma unroll
          for (int j = 0; j < 4; ++j) {
            int bb = 16 * w + kb * 4 + j;
            __hip_atomic_store(dst + (size_t)bb * 2304 + g0w + 16 * q + la,
                               acc[q][j] + bl96[16 * q + la],
                               __ATOMIC_RELAXED, __HIP_MEMORY_SCOPE_AGENT);
          }
      }
      bar_arrive(barA);
    }
    return;
  }

  if (wg < 136) {
    // ================= C1: layer-1 consumer (one batch) =================
    const int b = wg - 72;
    float hreg1[3], lw1[9], lb1[9];
#pragma unroll
    for (int g = 0; g < 3; ++g)
#pragma unroll
      for (int p = 0; p < 3; ++p) {
        int gi = g * 768 + tid + (p << 8);
        lw1[g * 3 + p] = lnw[gi];  lb1[g * 3 + p] = lnb[gi];
      }
#pragma unroll
    for (int p = 0; p < 3; ++p) {
      int i = tid + (p << 8);
      hreg1[p] = firstflag ? h0[(size_t)b * 768 + i] : hstate[(size_t)b * 768 + i];
    }
    WRRING(h1ring, 3, hreg1);    // (t0-1)&3 == 3 (t0 multiple of 4)
    bar_arrive(barB);

    for (int s = 0; s <= TC; ++s) {
      const int t1 = t0 + s;
      const bool doL1 = (s < TC);
      float x1v[9], xcur[3];
      if (doL1) {
        const float* xg1b = xg1 + ((size_t)b * TC + s) * 2304;
#pragma unroll
        for (int p = 0; p < 9; ++p) x1v[p] = xg1b[tid + p * 256];
#pragma unroll
        for (int p = 0; p < 3; ++p)
          xcur[p] = x[((size_t)b * 512 + t1) * 768 + tid + (p << 8)];
      }
      bar_wait(barA, 72u * (unsigned)(s + 1));

      if (doL1) {
        float g1v[9];
        {
          const float* p1 = hg1 + (size_t)b * 2304;
#pragma unroll
          for (int p = 0; p < 9; ++p) {
            const float* q1 = p1 + tid + p * 256;
            asm volatile("global_load_dword %0, %1, off sc0 sc1" : "=v"(g1v[p]) : "v"(q1));
          }
        }
        WAITV(0);

        float s11[3], s21[3];
        float v4[4] = {0, 0, 0, 0};
#pragma unroll
        for (int p = 0; p < 3; ++p) {
          s11[p] = g1v[p] + x1v[p];
          s21[p] = g1v[3 + p] + x1v[3 + p];
          v4[0] += s11[p]; v4[1] += s11[p] * s11[p];
          v4[2] += s21[p]; v4[3] += s21[p] * s21[p];
        }
        blk_reduce<4>(v4, redl);
        float mu1 = v4[0] * INV768, rs1 = rsqrtf(v4[1] * INV768 - mu1 * mu1 + EPS);
        float mu2 = v4[2] * INV768, rs2 = rsqrtf(v4[3] * INV768 - mu2 * mu2 + EPS);

        float z1[3], m1[3];
        float v2[2] = {0, 0};
#pragma unroll
        for (int p = 0; p < 3; ++p) {
          float r1 = sigf((s11[p] - mu1) * rs1 * lw1[p] + lb1[p]);
          z1[p]    = sigf((s21[p] - mu2) * rs2 * lw1[3 + p] + lb1[3 + p]);
          m1[p] = x1v[6 + p] + r1 * g1v[6 + p];
          v2[0] += m1[p]; v2[1] += m1[p] * m1[p];
        }
        blk_reduce<2>(v2, redl);
        float mum = v2[0] * INV768, rsm = rsqrtf(v2[1] * INV768 - mum * mum + EPS);

        float h1new[3], s1new[3];
#pragma unroll
        for (int p = 0; p < 3; ++p) {
          float n1 = tanhf((m1[p] - mum) * rsm * lw1[6 + p] + lb1[6 + p]);
          h1new[p] = (1.f - z1[p]) * n1 + z1[p] * hreg1[p];
          s1new[p] = h1new[p] + xcur[p];
          hreg1[p] = h1new[p];
        }
        WRRING(h1ring, t1, h1new);
        WRRING(s1ring, t1, s1new);
      }
      bar_arrive(barB);
    }

#pragma unroll
    for (int p = 0; p < 3; ++p) {
      int i = tid + (p << 8);
      hstate[(size_t)b * 768 + i] = hreg1[p];
      if (lastflag) hfin[(size_t)b * 768 + i] = hreg1[p];
    }
    return;
  }

  // ================= C2: layer-2 consumer (one batch) =================
  {
    const int b = wg - 136;
    float hreg2[3], lw2[9], lb2[9];
#pragma unroll
    for (int g = 0; g < 3; ++g)
#pragma unroll
      for (int p = 0; p < 3; ++p) {
        int gi = 2304 + g * 768 + tid + (p << 8);
        lw2[g * 3 + p] = lnw[gi];  lb2[g * 3 + p] = lnb[gi];
      }
#pragma unroll
    for (int p = 0; p < 3; ++p) {
      int i = tid + (p << 8);
      hreg2[p] = firstflag ? h0[49152 + (size_t)b * 768 + i]
                           : hstate[49152 + (size_t)b * 768 + i];
    }
    WRRING(h2ring, 3, hreg2);    // (t0-1)&3 == 3
    bar_arrive(barB);

    for (int s = 0; s <= TC; ++s) {
      const bool doL2 = (s >= 1);
      const int t2 = t0 + s - 1;
      bar_wait(barA, 72u * (unsigned)(s + 1));

      float seqv[3];
      if (doL2) {
        float g2v[9], g3v[9];
        unsigned s1raw[3];   // asm loads DIRECTLY into these; consumed after WAITV
        {
          const float* p2 = xg2 + (size_t)b * 2304;
          const float* p3 = hg2 + (size_t)b * 2304;
#pragma unroll
          for (int p = 0; p < 9; ++p) {
            const float* q2 = p2 + tid + p * 256;
            const float* q3 = p3 + tid + p * 256;
            asm volatile("global_load_dword %0, %1, off sc0 sc1" : "=v"(g2v[p]) : "v"(q2));
            asm volatile("global_load_dword %0, %1, off sc0 sc1" : "=v"(g3v[p]) : "v"(q3));
          }
          const unsigned* rp = s1ring + (unsigned)(t2 & 3) * SLOT;
#pragma unroll
          for (int p = 0; p < 3; ++p) {
            int i = tid + (p << 8);
            const unsigned* qs = rp + (i >> 3) * 256 + b * 4 + ((i >> 1) & 3);
            asm volatile("global_load_dword %0, %1, off sc0 sc1" : "=v"(s1raw[p]) : "v"(qs));
          }
        }
        WAITV(0);
        float s1v[3];
        const bool hi = (tid & 1);
#pragma unroll
        for (int p = 0; p < 3; ++p)
          s1v[p] = hi ? u2f(s1raw[p] & 0xFFFF0000u) : u2f(s1raw[p] << 16);

        float s12[3], s22[3];
        float v4[4] = {0, 0, 0, 0};
#pragma unroll
        for (int p = 0; p < 3; ++p) {
          s12[p] = g2v[p] + g3v[p];
          s22[p] = g2v[3 + p] + g3v[3 + p];
          v4[0] += s12[p]; v4[1] += s12[p] * s12[p];
          v4[2] += s22[p]; v4[3] += s22[p] * s22[p];
        }
        blk_reduce<4>(v4, redl);
        float mu1 = v4[0] * INV768, rs1 = rsqrtf(v4[1] * INV768 - mu1 * mu1 + EPS);
        float mu2 = v4[2] * INV768, rs2 = rsqrtf(v4[3] * INV768 - mu2 * mu2 + EPS);

        float z2[3], m2[3];
        float v2[2] = {0, 0};
#pragma unroll
        for (int p = 0; p < 3; ++p) {
          float r2 = sigf((s12[p] - mu1) * rs1 * lw2[p] + lb2[p]);
          z2[p]    = sigf((s22[p] - mu2) * rs2 * lw2[3 + p] + lb2[3 + p]);
          m2[p] = g2v[6 + p] + r2 * g3v[6 + p];
          v2[0] += m2[p]; v2[1] += m2[p] * m2[p];
        }
        blk_reduce<2>(v2, redl);
        float mum = v2[0] * INV768, rsm = rsqrtf(v2[1] * INV768 - mum * mum + EPS);

        float h2new[3];
#pragma unroll
        for (int p = 0; p < 3; ++p) {
          float n2 = tanhf((m2[p] - mum) * rsm * lw2[6 + p] + lb2[6 + p]);
          h2new[p] = (1.f - z2[p]) * n2 + z2[p] * hreg2[p];
          hreg2[p] = h2new[p];
          seqv[p] = h2new[p] + s1v[p];
        }
        WRRING(h2ring, t2, h2new);
      }
      bar_arrive(barB);
      if (doL2) {
#pragma unroll
        for (int p = 0; p < 3; ++p) {
          int i = tid + (p << 8);
          seq[((size_t)b * 512 + t2) * 768 + i] = seqv[p];
        }
      }
    }

#pragma unroll
    for (int p = 0; p < 3; ++p) {
      int i = tid + (p << 8);
      hstate[49152 + (size_t)b * 768 + i] = hreg2[p];
      if (lastflag) hfin[49152 + (size_t)b * 768 + i] = hreg2[p];
    }
  }
}

extern "C" void kernel_launch(void* const* d_in, const int* in_sizes, int n_in,
                              void* d_out, int out_size, void* d_ws, size_t ws_size,
                              hipStream_t stream) {
  const float* x    = (const float*)d_in[0];
  const float* h0   = (const float*)d_in[1];
  const float* w_ih = (const float*)d_in[2];
  const float* b_ih = (const float*)d_in[3];
  const float* w_hh = (const float*)d_in[4];
  const float* b_hh = (const float*)d_in[5];
  const float* lnw  = (const float*)d_in[6];
  const float* lnb  = (const float*)d_in[7];
  float* out = (float*)d_out;

  const int B = 64, T = 512, H = 768, G = 2304;

  const size_t BAR = 65536;
  const size_t RING = 4u * SLOT * 4u;       // 393,216 B per ring (depth 4)
  const size_t HGB = (size_t)B * G * 4;     // 589,824 B
  int CHUNK = 128;
  for (;;) {
    size_t need = BAR + 3 * RING + 3 * HGB + 2 * (size_t)B * H * 4
                + (size_t)B * CHUNK * G * 4;
    if (need <= ws_size || CHUNK == 8) break;
    CHUNK >>= 1;
  }

  char* wp = (char*)d_ws;
  unsigned* barctr = (unsigned*)wp;            wp += BAR;
  unsigned* h1ring = (unsigned*)wp;            wp += RING;
  unsigned* s1ring = (unsigned*)wp;            wp += RING;
  unsigned* h2ring = (unsigned*)wp;            wp += RING;
  float* hg1 = (float*)wp;                     wp += HGB;
  float* xg2 = (float*)wp;                     wp += HGB;
  float* hg2 = (float*)wp;                     wp += HGB;
  float* hstate = (float*)wp;                  wp += 2 * (size_t)B * H * 4;
  float* xg1 = (float*)wp;

  hipMemsetAsync(barctr, 0, BAR, stream);

  float* seq  = out;
  float* hfin = out + (size_t)B * T * H;
  const int NCH = T / CHUNK;

  const float* Wih1 = w_ih;
  const float* Wih2 = w_ih + (size_t)G * H;
  const float* Whh1 = w_hh;
  const float* Whh2 = w_hh + (size_t)G * H;

  for (int c = 0; c < NCH; ++c) {
    int t0 = c * CHUNK;
    gemm_bt<<<dim3(G / 64, B, CHUNK / 64), 256, 0, stream>>>(
        x + (size_t)t0 * H, (size_t)T * H, Wih1, b_ih,
        xg1, (size_t)CHUNK * G, CHUNK);
    gru_super<<<NWGT, 256, 0, stream>>>(
        Whh1, b_hh, Wih2, b_ih + G, Whh2, b_hh + G,
        lnw, lnb, x, xg1, t0, CHUNK,
        h0, hstate, h1ring, s1ring, h2ring,
        hg1, xg2, hg2,
        barctr + (size_t)c * 1024,
        seq, hfin,
        (c == 0) ? 1 : 0, (c == NCH - 1) ? 1 : 0);
  }
}

// Round 19
// 6388.017 us; speedup vs baseline: 1.2264x; 1.0174x over previous
//
#include <hip/hip_runtime.h>

typedef short bf16x8 __attribute__((ext_vector_type(8)));
typedef float f32x4 __attribute__((ext_vector_type(4)));

__device__ __forceinline__ unsigned pack2bf(float a, float b) {
  union { float f; unsigned u; } x, y;
  x.f = a; y.f = b;
  unsigned ra = (x.u + 0x7FFFu + ((x.u >> 16) & 1u)) >> 16;
  unsigned rb = (y.u + 0x7FFFu + ((y.u >> 16) & 1u)) & 0xFFFF0000u;
  return ra | rb;
}
__device__ __forceinline__ unsigned short bfu(float f) {
  union { float f; unsigned u; } v; v.f = f;
  return (unsigned short)((v.u + 0x7FFFu + ((v.u >> 16) & 1u)) >> 16);
}
__device__ __forceinline__ float u2f(unsigned u) {
  union { unsigned u; float f; } v; v.u = u; return v.f;
}
__device__ __forceinline__ float sigf(float x) { return 1.f / (1.f + __expf(-x)); }

#define KB 64
#define LDSP 72

// ---------------- xg GEMM for layer 1 (proven; M tiled by blockIdx.z) ----------------
__global__ __launch_bounds__(256) void gemm_bt(
    const float* __restrict__ A0, size_t a_bstride,
    const float* __restrict__ W,
    const float* __restrict__ bias,
    float* __restrict__ out, size_t o_bstride,
    int Mvalid)
{
  __shared__ unsigned short As[64][LDSP];
  __shared__ unsigned short Bs[64][LDSP];
  const int tid = threadIdx.x;
  const int g0 = blockIdx.x * 64;
  const int mlo = blockIdx.z * 64;
  const float* Ab = A0 + (size_t)blockIdx.y * a_bstride + (size_t)mlo * 768;
  float* outb = out + (size_t)blockIdx.y * o_bstride + (size_t)mlo * 2304;

  const int srow = tid >> 2;
  const int scol = (tid & 3) << 4;
  const int wv = tid >> 6;
  const int lane = tid & 63;
  const int wr = wv >> 1, wc = wv & 1;
  const int lrow = lane & 15;
  const int lk = (lane >> 4) << 3;

  f32x4 acc[2][2];
#pragma unroll
  for (int i = 0; i < 2; ++i)
#pragma unroll
    for (int j = 0; j < 2; ++j)
      acc[i][j] = (f32x4){0.f, 0.f, 0.f, 0.f};

  const float* Aptr = Ab + (size_t)srow * 768 + scol;
  const float* Bptr = W + ((size_t)(g0 + srow)) * 768 + scol;
  const bool aval = (mlo + srow) < Mvalid;

  for (int k0 = 0; k0 < 768; k0 += KB) {
    uint4 ua0, ua1, ub0, ub1;
    if (aval) {
      const float4* qa = (const float4*)(Aptr + k0);
      float4 f0 = qa[0], f1 = qa[1], f2 = qa[2], f3 = qa[3];
      ua0 = make_uint4(pack2bf(f0.x, f0.y), pack2bf(f0.z, f0.w),
                       pack2bf(f1.x, f1.y), pack2bf(f1.z, f1.w));
      ua1 = make_uint4(pack2bf(f2.x, f2.y), pack2bf(f2.z, f2.w),
                       pack2bf(f3.x, f3.y), pack2bf(f3.z, f3.w));
    } else {
      ua0 = make_uint4(0u, 0u, 0u, 0u);
      ua1 = ua0;
    }
    {
      const float4* qb = (const float4*)(Bptr + k0);
      float4 f0 = qb[0], f1 = qb[1], f2 = qb[2], f3 = qb[3];
      ub0 = make_uint4(pack2bf(f0.x, f0.y), pack2bf(f0.z, f0.w),
                       pack2bf(f1.x, f1.y), pack2bf(f1.z, f1.w));
      ub1 = make_uint4(pack2bf(f2.x, f2.y), pack2bf(f2.z, f2.w),
                       pack2bf(f3.x, f3.y), pack2bf(f3.z, f3.w));
    }
    __syncthreads();
    *(uint4*)&As[srow][scol] = ua0;
    *(uint4*)&As[srow][scol + 8] = ua1;
    *(uint4*)&Bs[srow][scol] = ub0;
    *(uint4*)&Bs[srow][scol + 8] = ub1;
    __syncthreads();
#pragma unroll
    for (int kh = 0; kh < 2; ++kh) {
      bf16x8 a0 = *(const bf16x8*)&As[32 * wr + lrow][32 * kh + lk];
      bf16x8 a1 = *(const bf16x8*)&As[32 * wr + 16 + lrow][32 * kh + lk];
      bf16x8 b0 = *(const bf16x8*)&Bs[32 * wc + lrow][32 * kh + lk];
      bf16x8 b1 = *(const bf16x8*)&Bs[32 * wc + 16 + lrow][32 * kh + lk];
      acc[0][0] = __builtin_amdgcn_mfma_f32_16x16x32_bf16(a0, b0, acc[0][0], 0, 0, 0);
      acc[0][1] = __builtin_amdgcn_mfma_f32_16x16x32_bf16(a0, b1, acc[0][1], 0, 0, 0);
      acc[1][0] = __builtin_amdgcn_mfma_f32_16x16x32_bf16(a1, b0, acc[1][0], 0, 0, 0);
      acc[1][1] = __builtin_amdgcn_mfma_f32_16x16x32_bf16(a1, b1, acc[1][1], 0, 0, 0);
    }
  }

  const int lgrp = lane >> 4;
#pragma unroll
  for (int fr = 0; fr < 2; ++fr)
#pragma unroll
    for (int fc = 0; fc < 2; ++fc)
#pragma unroll
      for (int j = 0; j < 4; ++j) {
        int m = 32 * wr + 16 * fr + lgrp * 4 + j;
        int n = 32 * wc + 16 * fc + lrow;
        if (mlo + m < Mvalid)
          outb[(size_t)m * 2304 + g0 + n] = acc[fr][fc][j] + bias[g0 + n];
      }
}

// ---- R18 proven structure: 72 producers, 64 C1 (L1), 64 C2 (L2), ONE barrier pair ----
#define NWGT 200
#define EPS 1e-5f
#define INV768 (1.0f / 768.0f)
#define SLOT 24576u   // u32 words per ring slot (96*64*4)

__device__ __forceinline__ void bar_arrive(unsigned* c) {
  __syncthreads();  // drains vmcnt: sc1 stores at coherence point before arrive
  if (threadIdx.x == 0)
    __hip_atomic_fetch_add(c + (blockIdx.x & 7) * 32, 1u,
                           __ATOMIC_RELAXED, __HIP_MEMORY_SCOPE_AGENT);
}
__device__ __forceinline__ void bar_wait(unsigned* c, unsigned tgt) {
  if (threadIdx.x == 0) {
    for (;;) {
      unsigned s = 0;
#pragma unroll
      for (int i = 0; i < 8; ++i)
        s += __hip_atomic_load(c + i * 32, __ATOMIC_RELAXED, __HIP_MEMORY_SCOPE_AGENT);
      if (s >= tgt) break;
      __builtin_amdgcn_s_sleep(1);
    }
  }
  __syncthreads();
}

template <int N>
__device__ __forceinline__ void blk_reduce(float* v, float* lds) {
#pragma unroll
  for (int k = 0; k < N; ++k) {
    float x = v[k];
#pragma unroll
    for (int off = 1; off < 64; off <<= 1) x += __shfl_xor(x, off);
    v[k] = x;
  }
  const int wv = threadIdx.x >> 6;
  const int lane = threadIdx.x & 63;
  if (lane == 0) {
#pragma unroll
    for (int k = 0; k < N; ++k) lds[wv * N + k] = v[k];
  }
  __syncthreads();
#pragma unroll
  for (int k = 0; k < N; ++k)
    v[k] = lds[k] + lds[N + k] + lds[2 * N + k] + lds[3 * N + k];
  __syncthreads();
}

#define WAITV(n) do { asm volatile("s_waitcnt vmcnt(" #n ")" ::: "memory"); \
                      __builtin_amdgcn_sched_barrier(0); } while (0)

#define LD24(buf, base) \
  { _Pragma("unroll") for (int kk_ = 0; kk_ < 24; ++kk_) { \
      const unsigned* p_ = (base) + (size_t)kk_ * 1024u; \
      asm volatile("global_load_dwordx4 %0, %1, off sc0 sc1" : "=v"(buf[kk_]) : "v"(p_)); } }

#define WRRING(ring, t, val) \
  { unsigned* rp_ = (ring) + (unsigned)(((t) & 3)) * SLOT; \
    _Pragma("unroll") for (int p_ = 0; p_ < 3; ++p_) { \
      int i_ = tid + (p_ << 8); \
      float other_ = __shfl_xor(val[p_], 1); \
      if ((tid & 1) == 0) { \
        unsigned pk_ = pack2bf(val[p_], other_); \
        __hip_atomic_store(rp_ + (i_ >> 3) * 256 + b * 4 + ((i_ >> 1) & 3), pk_, \
                           __ATOMIC_RELAXED, __HIP_MEMORY_SCOPE_AGENT); } } }

__global__ __launch_bounds__(256, 1) void gru_super(
    const float* __restrict__ Whh1, const float* __restrict__ bhh1,
    const float* __restrict__ Wih2, const float* __restrict__ bih2,
    const float* __restrict__ Whh2, const float* __restrict__ bhh2,
    const float* __restrict__ lnw, const float* __restrict__ lnb,  // [2][3][768]
    const float* __restrict__ x,      // [64][512][768]
    const float* __restrict__ xg1,    // [64][TC][2304]
    int t0, int TC,
    const float* __restrict__ h0,     // [2][64][768]
    float* __restrict__ hstate,       // [2][64][768]
    unsigned* __restrict__ h1ring, unsigned* __restrict__ s1ring,
    unsigned* __restrict__ h2ring,
    float* __restrict__ hg1, float* __restrict__ xg2, float* __restrict__ hg2,
    unsigned* __restrict__ bar,
    float* __restrict__ seq,          // d_out [64][512][768]
    float* __restrict__ hfin,         // d_out tail [2][64][768]
    int firstflag, int lastflag)
{
  __shared__ unsigned short Wl[96][776];
  __shared__ float bl96[96];
  __shared__ float redl[32];

  unsigned* barA = bar;
  unsigned* barB = bar + 512;

  const int wg = blockIdx.x;
  const int tid = threadIdx.x;
  const int lane = tid & 63;
  const int w = tid >> 6;
  const int la = lane & 15;
  const int kb = lane >> 4;
  const int arow = 16 * w + la;

  if (wg < 72) {
    // ================= PRODUCERS =================
    const int mcls = wg / 24;            // 0: Whh1->hg1, 1: Wih2->xg2, 2: Whh2->hg2
    const int g0w = (wg % 24) * 96;
    const unsigned abase = (unsigned)((kb * 64 + arow) << 2);
    {
      const float* Wsrc = (mcls == 0) ? Whh1 : (mcls == 1) ? Wih2 : Whh2;
      const float* bsrc = (mcls == 0) ? bhh1 : (mcls == 1) ? bih2 : bhh2;
      for (int r = 0; r < 96; ++r) {
        const float* src = Wsrc + (size_t)(g0w + r) * 768;
        for (int c = tid; c < 768; c += 256) Wl[r][c] = bfu(src[c]);
      }
      if (tid < 96) bl96[tid] = bsrc[g0w + tid];
    }
    float* dst = (mcls == 0) ? hg1 : (mcls == 1) ? xg2 : hg2;

    for (int s = 0; s <= TC; ++s) {
      const int t1 = t0 + s;
      const bool doL1 = (s < TC);
      const bool doL2 = (s >= 1);
      const bool active = (mcls == 0) ? doL1 : doL2;
      bar_wait(barB, 128u * (unsigned)(s + 1));   // both consumer sets thru round s-1
      if (active) {
        const unsigned* rbase =
            (mcls == 0) ? (h1ring + (unsigned)((t1 - 1) & 3) * SLOT)
          : (mcls == 1) ? (s1ring + (unsigned)((t1 - 1) & 3) * SLOT)
                        : (h2ring + (unsigned)((t1 - 2) & 3) * SLOT);
        const unsigned* hb = rbase + abase;
        f32x4 acc[6];
#pragma unroll
        for (int q = 0; q < 6; ++q) acc[q] = (f32x4){0.f, 0.f, 0.f, 0.f};
        bf16x8 buf[24];
        LD24(buf, hb);
        WAITV(0);
#pragma unroll
        for (int kk = 0; kk < 24; ++kk) {
#pragma unroll
          for (int q = 0; q < 6; ++q) {
            bf16x8 wv2 = *(const bf16x8*)&Wl[16 * q + la][kk * 32 + kb * 8];
            acc[q] = __builtin_amdgcn_mfma_f32_16x16x32_bf16(buf[kk], wv2, acc[q], 0, 0, 0);
          }
        }
#pragma unroll
        for (int q = 0; q < 6; ++q)
#pragma unroll
          for (int j = 0; j < 4; ++j) {
            int bb = 16 * w + kb * 4 + j;
            __hip_atomic_store(dst + (size_t)bb * 2304 + g0w + 16 * q + la,
                               acc[q][j] + bl96[16 * q + la],
                               __ATOMIC_RELAXED, __HIP_MEMORY_SCOPE_AGENT);
          }
      }
      bar_arrive(barA);
    }
    return;
  }

  if (wg < 136) {
    // ================= C1: layer-1 consumer (one batch) =================
    const int b = wg - 72;
    float hreg1[3], lw1[9], lb1[9];
#pragma unroll
    for (int g = 0; g < 3; ++g)
#pragma unroll
      for (int p = 0; p < 3; ++p) {
        int gi = g * 768 + tid + (p << 8);
        lw1[g * 3 + p] = lnw[gi];  lb1[g * 3 + p] = lnb[gi];
      }
#pragma unroll
    for (int p = 0; p < 3; ++p) {
      int i = tid + (p << 8);
      hreg1[p] = firstflag ? h0[(size_t)b * 768 + i] : hstate[(size_t)b * 768 + i];
    }
    WRRING(h1ring, 3, hreg1);    // (t0-1)&3 == 3 (t0 multiple of 4)
    bar_arrive(barB);

    for (int s = 0; s <= TC; ++s) {
      const int t1 = t0 + s;
      const bool doL1 = (s < TC);
      float x1v[9], xcur[3];
      if (doL1) {
        const float* xg1b = xg1 + ((size_t)b * TC + s) * 2304;
#pragma unroll
        for (int p = 0; p < 9; ++p) x1v[p] = xg1b[tid + p * 256];
#pragma unroll
        for (int p = 0; p < 3; ++p)
          xcur[p] = x[((size_t)b * 512 + t1) * 768 + tid + (p << 8)];
      }
      bar_wait(barA, 72u * (unsigned)(s + 1));

      if (doL1) {
        float g1v[9];
        {
          const float* p1 = hg1 + (size_t)b * 2304;
#pragma unroll
          for (int p = 0; p < 9; ++p) {
            const float* q1 = p1 + tid + p * 256;
            asm volatile("global_load_dword %0, %1, off sc0 sc1" : "=v"(g1v[p]) : "v"(q1));
          }
        }
        WAITV(0);

        float s11[3], s21[3];
        float v4[4] = {0, 0, 0, 0};
#pragma unroll
        for (int p = 0; p < 3; ++p) {
          s11[p] = g1v[p] + x1v[p];
          s21[p] = g1v[3 + p] + x1v[3 + p];
          v4[0] += s11[p]; v4[1] += s11[p] * s11[p];
          v4[2] += s21[p]; v4[3] += s21[p] * s21[p];
        }
        blk_reduce<4>(v4, redl);
        float mu1 = v4[0] * INV768, rs1 = rsqrtf(v4[1] * INV768 - mu1 * mu1 + EPS);
        float mu2 = v4[2] * INV768, rs2 = rsqrtf(v4[3] * INV768 - mu2 * mu2 + EPS);

        float z1[3], m1[3];
        float v2[2] = {0, 0};
#pragma unroll
        for (int p = 0; p < 3; ++p) {
          float r1 = sigf((s11[p] - mu1) * rs1 * lw1[p] + lb1[p]);
          z1[p]    = sigf((s21[p] - mu2) * rs2 * lw1[3 + p] + lb1[3 + p]);
          m1[p] = x1v[6 + p] + r1 * g1v[6 + p];
          v2[0] += m1[p]; v2[1] += m1[p] * m1[p];
        }
        blk_reduce<2>(v2, redl);
        float mum = v2[0] * INV768, rsm = rsqrtf(v2[1] * INV768 - mum * mum + EPS);

        float h1new[3], s1new[3];
#pragma unroll
        for (int p = 0; p < 3; ++p) {
          float n1 = tanhf((m1[p] - mum) * rsm * lw1[6 + p] + lb1[6 + p]);
          h1new[p] = (1.f - z1[p]) * n1 + z1[p] * hreg1[p];
          s1new[p] = h1new[p] + xcur[p];
          hreg1[p] = h1new[p];
        }
        WRRING(h1ring, t1, h1new);
        WRRING(s1ring, t1, s1new);
      }
      bar_arrive(barB);
    }

#pragma unroll
    for (int p = 0; p < 3; ++p) {
      int i = tid + (p << 8);
      hstate[(size_t)b * 768 + i] = hreg1[p];
      if (lastflag) hfin[(size_t)b * 768 + i] = hreg1[p];
    }
    return;
  }

  // ================= C2: layer-2 consumer (one batch) =================
  {
    const int b = wg - 136;
    float hreg2[3], lw2[9], lb2[9];
#pragma unroll
    for (int g = 0; g < 3; ++g)
#pragma unroll
      for (int p = 0; p < 3; ++p) {
        int gi = 2304 + g * 768 + tid + (p << 8);
        lw2[g * 3 + p] = lnw[gi];  lb2[g * 3 + p] = lnb[gi];
      }
#pragma unroll
    for (int p = 0; p < 3; ++p) {
      int i = tid + (p << 8);
      hreg2[p] = firstflag ? h0[49152 + (size_t)b * 768 + i]
                           : hstate[49152 + (size_t)b * 768 + i];
    }
    WRRING(h2ring, 3, hreg2);    // (t0-1)&3 == 3
    bar_arrive(barB);

    for (int s = 0; s <= TC; ++s) {
      const bool doL2 = (s >= 1);
      const int t2 = t0 + s - 1;
      bar_wait(barA, 72u * (unsigned)(s + 1));

      float seqv[3];
      if (doL2) {
        float g2v[9], g3v[9];
        unsigned s1raw[3];   // asm loads DIRECTLY into these; consumed after WAITV
        {
          const float* p2 = xg2 + (size_t)b * 2304;
          const float* p3 = hg2 + (size_t)b * 2304;
#pragma unroll
          for (int p = 0; p < 9; ++p) {
            const float* q2 = p2 + tid + p * 256;
            const float* q3 = p3 + tid + p * 256;
            asm volatile("global_load_dword %0, %1, off sc0 sc1" : "=v"(g2v[p]) : "v"(q2));
            asm volatile("global_load_dword %0, %1, off sc0 sc1" : "=v"(g3v[p]) : "v"(q3));
          }
          const unsigned* rp = s1ring + (unsigned)(t2 & 3) * SLOT;
#pragma unroll
          for (int p = 0; p < 3; ++p) {
            int i = tid + (p << 8);
            const unsigned* qs = rp + (i >> 3) * 256 + b * 4 + ((i >> 1) & 3);
            asm volatile("global_load_dword %0, %1, off sc0 sc1" : "=v"(s1raw[p]) : "v"(qs));
          }
        }
        WAITV(0);
        float s1v[3];
        const bool hi = (tid & 1);
#pragma unroll
        for (int p = 0; p < 3; ++p)
          s1v[p] = hi ? u2f(s1raw[p] & 0xFFFF0000u) : u2f(s1raw[p] << 16);

        float s12[3], s22[3];
        float v4[4] = {0, 0, 0, 0};
#pragma unroll
        for (int p = 0; p < 3; ++p) {
          s12[p] = g2v[p] + g3v[p];
          s22[p] = g2v[3 + p] + g3v[3 + p];
          v4[0] += s12[p]; v4[1] += s12[p] * s12[p];
          v4[2] += s22[p]; v4[3] += s22[p] * s22[p];
        }
        blk_reduce<4>(v4, redl);
        float mu1 = v4[0] * INV768, rs1 = rsqrtf(v4[1] * INV768 - mu1 * mu1 + EPS);
        float mu2 = v4[2] * INV768, rs2 = rsqrtf(v4[3] * INV768 - mu2 * mu2 + EPS);

        float z2[3], m2[3];
        float v2[2] = {0, 0};
#pragma unroll
        for (int p = 0; p < 3; ++p) {
          float r2 = sigf((s12[p] - mu1) * rs1 * lw2[p] + lb2[p]);
          z2[p]    = sigf((s22[p] - mu2) * rs2 * lw2[3 + p] + lb2[3 + p]);
          m2[p] = g2v[6 + p] + r2 * g3v[6 + p];
          v2[0] += m2[p]; v2[1] += m2[p] * m2[p];
        }
        blk_reduce<2>(v2, redl);
        float mum = v2[0] * INV768, rsm = rsqrtf(v2[1] * INV768 - mum * mum + EPS);

        float h2new[3];
#pragma unroll
        for (int p = 0; p < 3; ++p) {
          float n2 = tanhf((m2[p] - mum) * rsm * lw2[6 + p] + lb2[6 + p]);
          h2new[p] = (1.f - z2[p]) * n2 + z2[p] * hreg2[p];
          hreg2[p] = h2new[p];
          seqv[p] = h2new[p] + s1v[p];
        }
        WRRING(h2ring, t2, h2new);
      }
      bar_arrive(barB);
      if (doL2) {
#pragma unroll
        for (int p = 0; p < 3; ++p) {
          int i = tid + (p << 8);
          seq[((size_t)b * 512 + t2) * 768 + i] = seqv[p];
        }
      }
    }

#pragma unroll
    for (int p = 0; p < 3; ++p) {
      int i = tid + (p << 8);
      hstate[49152 + (size_t)b * 768 + i] = hreg2[p];
      if (lastflag) hfin[49152 + (size_t)b * 768 + i] = hreg2[p];
    }
  }
}

extern "C" void kernel_launch(void* const* d_in, const int* in_sizes, int n_in,
                              void* d_out, int out_size, void* d_ws, size_t ws_size,
                              hipStream_t stream) {
  const float* x    = (const float*)d_in[0];
  const float* h0   = (const float*)d_in[1];
  const float* w_ih = (const float*)d_in[2];
  const float* b_ih = (const float*)d_in[3];
  const float* w_hh = (const float*)d_in[4];
  const float* b_hh = (const float*)d_in[5];
  const float* lnw  = (const float*)d_in[6];
  const float* lnb  = (const float*)d_in[7];
  float* out = (float*)d_out;

  const int B = 64, T = 512, H = 768, G = 2304;

  const size_t BAR = 65536;
  const size_t RING = 4u * SLOT * 4u;       // 393,216 B per ring (depth 4)
  const size_t HGB = (size_t)B * G * 4;     // 589,824 B
  int CHUNK = 256;
  for (;;) {
    size_t need = BAR + 3 * RING + 3 * HGB + 2 * (size_t)B * H * 4
                + (size_t)B * CHUNK * G * 4;
    if (need <= ws_size || CHUNK == 8) break;
    CHUNK >>= 1;
  }

  char* wp = (char*)d_ws;
  unsigned* barctr = (unsigned*)wp;            wp += BAR;
  unsigned* h1ring = (unsigned*)wp;            wp += RING;
  unsigned* s1ring = (unsigned*)wp;            wp += RING;
  unsigned* h2ring = (unsigned*)wp;            wp += RING;
  float* hg1 = (float*)wp;                     wp += HGB;
  float* xg2 = (float*)wp;                     wp += HGB;
  float* hg2 = (float*)wp;                     wp += HGB;
  float* hstate = (float*)wp;                  wp += 2 * (size_t)B * H * 4;
  float* xg1 = (float*)wp;

  hipMemsetAsync(barctr, 0, BAR, stream);

  float* seq  = out;
  float* hfin = out + (size_t)B * T * H;
  const int NCH = T / CHUNK;

  const float* Wih1 = w_ih;
  const float* Wih2 = w_ih + (size_t)G * H;
  const float* Whh1 = w_hh;
  const float* Whh2 = w_hh + (size_t)G * H;

  for (int c = 0; c < NCH; ++c) {
    int t0 = c * CHUNK;
    gemm_bt<<<dim3(G / 64, B, CHUNK / 64), 256, 0, stream>>>(
        x + (size_t)t0 * H, (size_t)T * H, Wih1, b_ih,
        xg1, (size_t)CHUNK * G, CHUNK);
    gru_super<<<NWGT, 256, 0, stream>>>(
        Whh1, b_hh, Wih2, b_ih + G, Whh2, b_hh + G,
        lnw, lnb, x, xg1, t0, CHUNK,
        h0, hstate, h1ring, s1ring, h2ring,
        hg1, xg2, hg2,
        barctr + (size_t)c * 1024,
        seq, hfin,
        (c == 0) ? 1 : 0, (c == NCH - 1) ? 1 : 0);
  }
}